// Round 1
// baseline (451.935 us; speedup 1.0000x reference)
//
#include <hip/hip_runtime.h>
#include <math.h>

#define B_SZ   4
#define N_SEQ  197
#define DIMC   2048
#define HEADS  32
#define HD     64
#define WIN    8
#define M_ROWS (B_SZ * N_SEQ)   // 788

using f32x4 = __attribute__((ext_vector_type(4))) float;
using s16x8 = __attribute__((ext_vector_type(8))) short;

__device__ inline ushort f2bf(float f) {
  uint x = __float_as_uint(f);
  uint r = (x + 0x7fffu + ((x >> 16) & 1u)) >> 16;  // RNE
  return (ushort)r;
}
__device__ inline float bf2f(ushort u) {
  return __uint_as_float(((uint)u) << 16);
}

// ---------------- GEMM: C = A(fp32, MxK) @ Bw(fp32, NxK)^T ------------------
// OUT_F32=0: write bf16 (ushort) C; OUT_F32=1: write fp32 C + bias[col].
#define BM 128
#define BN 128
#define BK 32
#define LDST 40   // BK + 8 elem pad -> 80B row stride; 2-way LDS conflicts (free)

template<int OUT_F32>
__global__ __launch_bounds__(256)
void gemm_bt(const float* __restrict__ A, const float* __restrict__ Bw,
             void* __restrict__ Cout, const float* __restrict__ bias,
             int Mdim, int Ndim, int Kdim) {
  __shared__ ushort As[BM * LDST];
  __shared__ ushort Bs[BN * LDST];
  const int tid  = threadIdx.x;
  const int lane = tid & 63;
  const int wave = tid >> 6;
  const int m0 = blockIdx.x * BM;
  const int n0 = blockIdx.y * BN;
  const int wr = (wave >> 1) * 64;   // wave sub-tile origin (64x64)
  const int wc = (wave & 1) * 64;
  const int fr = lane & 15;          // fragment row/col index
  const int kg = lane >> 4;          // k-group 0..3

  f32x4 acc[4][4];
#pragma unroll
  for (int i = 0; i < 4; ++i)
#pragma unroll
    for (int j = 0; j < 4; ++j)
      acc[i][j] = (f32x4){0.f, 0.f, 0.f, 0.f};

  const int sr = tid >> 3;        // staging row within 32-row pass
  const int sc = (tid & 7) * 4;   // staging col (4 floats)

  for (int k0 = 0; k0 < Kdim; k0 += BK) {
#pragma unroll
    for (int p = 0; p < 4; ++p) {
      int r = p * 32 + sr;
      {
        int grow = m0 + r;
        f32x4 v = (f32x4){0.f, 0.f, 0.f, 0.f};
        if (grow < Mdim) v = *(const f32x4*)(A + (size_t)grow * Kdim + k0 + sc);
        ushort4 u;
        u.x = f2bf(v.x); u.y = f2bf(v.y); u.z = f2bf(v.z); u.w = f2bf(v.w);
        *(ushort4*)(&As[r * LDST + sc]) = u;
      }
      {
        int grow = n0 + r;
        f32x4 v = (f32x4){0.f, 0.f, 0.f, 0.f};
        if (grow < Ndim) v = *(const f32x4*)(Bw + (size_t)grow * Kdim + k0 + sc);
        ushort4 u;
        u.x = f2bf(v.x); u.y = f2bf(v.y); u.z = f2bf(v.z); u.w = f2bf(v.w);
        *(ushort4*)(&Bs[r * LDST + sc]) = u;
      }
    }
    __syncthreads();
    s16x8 af[4], bfr[4];
#pragma unroll
    for (int i = 0; i < 4; ++i)
      af[i] = *(const s16x8*)(&As[(wr + i * 16 + fr) * LDST + kg * 8]);
#pragma unroll
    for (int j = 0; j < 4; ++j)
      bfr[j] = *(const s16x8*)(&Bs[(wc + j * 16 + fr) * LDST + kg * 8]);
#pragma unroll
    for (int i = 0; i < 4; ++i)
#pragma unroll
      for (int j = 0; j < 4; ++j)
        acc[i][j] = __builtin_amdgcn_mfma_f32_16x16x32_bf16(af[i], bfr[j], acc[i][j], 0, 0, 0);
    __syncthreads();
  }

  // C/D layout (m89-verified): col = lane&15, row = (lane>>4)*4 + reg
  const int crow_base = m0 + wr + (lane >> 4) * 4;
  const int ccol_base = n0 + wc + fr;
  if constexpr (OUT_F32) {
    float* C = (float*)Cout;
#pragma unroll
    for (int j = 0; j < 4; ++j) {
      int col = ccol_base + j * 16;
      float bv = bias[col];
#pragma unroll
      for (int i = 0; i < 4; ++i)
#pragma unroll
        for (int r = 0; r < 4; ++r) {
          int grow = crow_base + i * 16 + r;
          if (grow < Mdim) C[(size_t)grow * Ndim + col] = acc[i][j][r] + bv;
        }
    }
  } else {
    ushort* C = (ushort*)Cout;
#pragma unroll
    for (int j = 0; j < 4; ++j) {
      int col = ccol_base + j * 16;
#pragma unroll
      for (int i = 0; i < 4; ++i)
#pragma unroll
        for (int r = 0; r < 4; ++r) {
          int grow = crow_base + i * 16 + r;
          if (grow < Mdim) C[(size_t)grow * Ndim + col] = f2bf(acc[i][j][r]);
        }
    }
  }
}

// ---------------- Local attention: one wave per (b, i, h) -------------------
// qkv bf16 layout: row = b*N+i (788 rows), col = three*2048 + h*64 + d
__global__ __launch_bounds__(256)
void local_attn(const ushort* __restrict__ qkv, float* __restrict__ ao) {
  const int gw = blockIdx.x * 4 + (threadIdx.x >> 6);
  if (gw >= B_SZ * HEADS * N_SEQ) return;
  const int lane = threadIdx.x & 63;
  const int h = gw % HEADS;
  const int t = gw / HEADS;
  const int i = t % N_SEQ;
  const int b = t / N_SEQ;
  const int row = b * N_SEQ + i;
  const size_t stride = 3 * DIMC;  // 6144

  const float q = bf2f(qkv[(size_t)row * stride + h * HD + lane]) * 0.125f;  // fold scale
  int j0 = i - WIN; if (j0 < 0) j0 = 0;
  int j1 = i + WIN; if (j1 > N_SEQ) j1 = N_SEQ;   // window [j0, j1)

  float s[16];
#pragma unroll
  for (int jj = 0; jj < 16; ++jj) {
    int j = j0 + jj;
    bool ok = (j < j1);
    int jc = ok ? j : (j1 - 1);  // clamped safe address
    float kd = bf2f(qkv[(size_t)(b * N_SEQ + jc) * stride + DIMC + h * HD + lane]);
    float p = q * kd;
#pragma unroll
    for (int o = 32; o > 0; o >>= 1) p += __shfl_xor(p, o);
    float d = fabsf((float)(i - j));
    float m = 1.0f - d * 0.0625f;    // (W - d/2)/W, always > 0 inside window
    s[jj] = ok ? p * m : -INFINITY;
  }

  float mx = -INFINITY;
#pragma unroll
  for (int jj = 0; jj < 16; ++jj) mx = fmaxf(mx, s[jj]);
  float sum = 0.f;
#pragma unroll
  for (int jj = 0; jj < 16; ++jj) { float e = expf(s[jj] - mx); s[jj] = e; sum += e; }
  const float inv = 1.f / sum;

  float o = 0.f;
#pragma unroll
  for (int jj = 0; jj < 16; ++jj) {
    int j = j0 + jj;
    if (j < j1)
      o += s[jj] * bf2f(qkv[(size_t)(b * N_SEQ + j) * stride + 2 * DIMC + h * HD + lane]);
  }
  ao[(size_t)row * DIMC + h * HD + lane] = o * inv;
}

// ----------------------------------------------------------------------------
extern "C" void kernel_launch(void* const* d_in, const int* in_sizes, int n_in,
                              void* d_out, int out_size, void* d_ws, size_t ws_size,
                              hipStream_t stream) {
  const float* x      = (const float*)d_in[0];
  const float* qkv_w  = (const float*)d_in[1];
  const float* proj_w = (const float*)d_in[2];
  const float* proj_b = (const float*)d_in[3];
  float* out = (float*)d_out;

  // ws layout: qkv bf16 (788 x 6144), then ao fp32 (788 x 2048)
  ushort* qkv = (ushort*)d_ws;
  size_t qkv_bytes = ((size_t)M_ROWS * 3 * DIMC * sizeof(ushort) + 255) & ~(size_t)255;
  float* ao = (float*)((char*)d_ws + qkv_bytes);

  dim3 blk(256);
  // QKV GEMM: (788 x 2048) @ (6144 x 2048)^T -> bf16 (788 x 6144)
  gemm_bt<0><<<dim3((M_ROWS + BM - 1) / BM, (3 * DIMC) / BN), blk, 0, stream>>>(
      x, qkv_w, (void*)qkv, nullptr, M_ROWS, 3 * DIMC, DIMC);
  // Local attention -> ao fp32 (788 x 2048)
  int total_waves = B_SZ * HEADS * N_SEQ;  // 25216
  local_attn<<<dim3((total_waves + 3) / 4), blk, 0, stream>>>(qkv, ao);
  // Proj GEMM: (788 x 2048) @ (2048 x 2048)^T + bias -> fp32 d_out
  gemm_bt<1><<<dim3((M_ROWS + BM - 1) / BM, DIMC / BN), blk, 0, stream>>>(
      ao, proj_w, (void*)out, proj_b, M_ROWS, DIMC, DIMC);
}

// Round 2
// 163.216 us; speedup vs baseline: 2.7689x; 2.7689x over previous
//
#include <hip/hip_runtime.h>
#include <math.h>

#define B_SZ   4
#define N_SEQ  197
#define DIMC   2048
#define HEADS  32
#define HD     64
#define WIN    8
#define M_ROWS (B_SZ * N_SEQ)   // 788
#define M_PAD  896               // 7 * 128

using f32x4 = __attribute__((ext_vector_type(4))) float;
using s16x8 = __attribute__((ext_vector_type(8))) short;

__device__ inline ushort f2bf(float f) {
  uint x = __float_as_uint(f);
  uint r = (x + 0x7fffu + ((x >> 16) & 1u)) >> 16;  // RNE
  return (ushort)r;
}
__device__ inline float bf2f(ushort u) {
  return __uint_as_float(((uint)u) << 16);
}

__device__ inline void gload16(const ushort* g, ushort* l) {
  __builtin_amdgcn_global_load_lds(
      (const __attribute__((address_space(1))) unsigned int*)g,
      (__attribute__((address_space(3))) unsigned int*)l, 16, 0, 0);
}

// ---------------- fp32 -> bf16 conversion (8 elems/thread) ------------------
__global__ __launch_bounds__(256)
void cvt_bf16(const float* __restrict__ src, ushort* __restrict__ dst, int n8) {
  int i = blockIdx.x * 256 + threadIdx.x;
  if (i >= n8) return;
  f32x4 a = ((const f32x4*)src)[2 * i];
  f32x4 b = ((const f32x4*)src)[2 * i + 1];
  ushort4 u0, u1;
  u0.x = f2bf(a.x); u0.y = f2bf(a.y); u0.z = f2bf(a.z); u0.w = f2bf(a.w);
  u1.x = f2bf(b.x); u1.y = f2bf(b.y); u1.z = f2bf(b.z); u1.w = f2bf(b.w);
  ((ushort4*)dst)[2 * i]     = u0;
  ((ushort4*)dst)[2 * i + 1] = u1;
}

// ------- GEMM (m97 structure): C = A(bf16, MxK) @ Bw(bf16, NxK)^T -----------
// A must be padded to a multiple of 128 rows (readable garbage OK).
// OUT_BF16=1: write bf16 C; else fp32 C + bias[col].
template<int OUT_BF16>
__global__ __launch_bounds__(256)
void gemm_bt_bf16(const ushort* __restrict__ A, const ushort* __restrict__ Bw,
                  void* __restrict__ Cout, const float* __restrict__ bias,
                  int Mdim, int Ndim, int Kdim) {
  __shared__ ushort As[128 * 32];
  __shared__ ushort Bs[128 * 32];
  const int tid  = threadIdx.x;
  const int lane = tid & 63;
  const int wave = tid >> 6;
  const int m0 = blockIdx.x * 128;
  const int n0 = blockIdx.y * 128;
  const int wr = (wave >> 1) * 64;   // wave output sub-tile (64x64)
  const int wc = (wave & 1) * 64;
  const int fr = lane & 15;
  const int kg = lane >> 4;
  const int srow = lane >> 2;        // staging: row within 16-row chunk
  const int scol = (lane & 3) * 8;   // staging: col (8 bf16 = 16B)

  f32x4 acc[4][4];
#pragma unroll
  for (int i = 0; i < 4; ++i)
#pragma unroll
    for (int j = 0; j < 4; ++j)
      acc[i][j] = (f32x4){0.f, 0.f, 0.f, 0.f};

  for (int k0 = 0; k0 < Kdim; k0 += 32) {
    __syncthreads();   // LDS free before overwrite
#pragma unroll
    for (int q = 0; q < 2; ++q) {
      const int c = wave * 2 + q;    // 16-row chunk, wave-uniform
      gload16(A  + (size_t)(m0 + c * 16 + srow) * Kdim + k0 + scol,
              (ushort*)As + c * 512);
      gload16(Bw + (size_t)(n0 + c * 16 + srow) * Kdim + k0 + scol,
              (ushort*)Bs + c * 512);
    }
    __syncthreads();   // drains vmcnt -> LDS ready
    s16x8 af[4], bfr[4];
#pragma unroll
    for (int i = 0; i < 4; ++i)
      af[i] = *(const s16x8*)(&As[(wr + i * 16 + fr) * 32 + kg * 8]);
#pragma unroll
    for (int j = 0; j < 4; ++j)
      bfr[j] = *(const s16x8*)(&Bs[(wc + j * 16 + fr) * 32 + kg * 8]);
#pragma unroll
    for (int i = 0; i < 4; ++i)
#pragma unroll
      for (int j = 0; j < 4; ++j)
        acc[i][j] = __builtin_amdgcn_mfma_f32_16x16x32_bf16(af[i], bfr[j], acc[i][j], 0, 0, 0);
  }

  // C/D layout: col = lane&15, row = (lane>>4)*4 + reg
  const int crow_base = m0 + wr + (lane >> 4) * 4;
  const int ccol_base = n0 + wc + fr;
  if constexpr (OUT_BF16) {
    ushort* C = (ushort*)Cout;
#pragma unroll
    for (int j = 0; j < 4; ++j) {
      int col = ccol_base + j * 16;
#pragma unroll
      for (int i = 0; i < 4; ++i)
#pragma unroll
        for (int r = 0; r < 4; ++r) {
          int grow = crow_base + i * 16 + r;
          if (grow < Mdim) C[(size_t)grow * Ndim + col] = f2bf(acc[i][j][r]);
        }
    }
  } else {
    float* C = (float*)Cout;
#pragma unroll
    for (int j = 0; j < 4; ++j) {
      int col = ccol_base + j * 16;
      float bv = bias[col];
#pragma unroll
      for (int i = 0; i < 4; ++i)
#pragma unroll
        for (int r = 0; r < 4; ++r) {
          int grow = crow_base + i * 16 + r;
          if (grow < Mdim) C[(size_t)grow * Ndim + col] = acc[i][j][r] + bv;
        }
    }
  }
}

// ---------------- Local attention: one wave per (b, i, h) -------------------
// qkv bf16 layout: row = b*N+i (788 rows), col = three*2048 + h*64 + d
__global__ __launch_bounds__(256)
void local_attn(const ushort* __restrict__ qkv, ushort* __restrict__ ao) {
  const int gw = blockIdx.x * 4 + (threadIdx.x >> 6);
  if (gw >= B_SZ * HEADS * N_SEQ) return;
  const int lane = threadIdx.x & 63;
  const int h = gw % HEADS;
  const int t = gw / HEADS;
  const int i = t % N_SEQ;
  const int b = t / N_SEQ;
  const int row = b * N_SEQ + i;
  const size_t stride = 3 * DIMC;

  const float q = bf2f(qkv[(size_t)row * stride + h * HD + lane]) * 0.125f;  // fold scale
  int j0 = i - WIN; if (j0 < 0) j0 = 0;
  int j1 = i + WIN; if (j1 > N_SEQ) j1 = N_SEQ;   // [j0, j1)

  float s[16];
#pragma unroll
  for (int jj = 0; jj < 16; ++jj) {
    int j = j0 + jj;
    bool ok = (j < j1);
    int jc = ok ? j : (j1 - 1);
    float kd = bf2f(qkv[(size_t)(b * N_SEQ + jc) * stride + DIMC + h * HD + lane]);
    float p = q * kd;
#pragma unroll
    for (int o = 32; o > 0; o >>= 1) p += __shfl_xor(p, o);
    float d = fabsf((float)(i - j));
    float m = 1.0f - d * 0.0625f;    // (W - d/2)/W
    s[jj] = ok ? p * m : -INFINITY;
  }

  float mx = -INFINITY;
#pragma unroll
  for (int jj = 0; jj < 16; ++jj) mx = fmaxf(mx, s[jj]);
  float sum = 0.f;
#pragma unroll
  for (int jj = 0; jj < 16; ++jj) { float e = expf(s[jj] - mx); s[jj] = e; sum += e; }
  const float inv = 1.f / sum;

  float o = 0.f;
#pragma unroll
  for (int jj = 0; jj < 16; ++jj) {
    int j = j0 + jj;
    if (j < j1)
      o += s[jj] * bf2f(qkv[(size_t)(b * N_SEQ + j) * stride + 2 * DIMC + h * HD + lane]);
  }
  ao[(size_t)row * DIMC + h * HD + lane] = f2bf(o * inv);
}

// ----------------------------------------------------------------------------
extern "C" void kernel_launch(void* const* d_in, const int* in_sizes, int n_in,
                              void* d_out, int out_size, void* d_ws, size_t ws_size,
                              hipStream_t stream) {
  const float* x      = (const float*)d_in[0];
  const float* qkv_w  = (const float*)d_in[1];
  const float* proj_w = (const float*)d_in[2];
  const float* proj_b = (const float*)d_in[3];
  float* out = (float*)d_out;

  // ws layout (bytes, all 256-aligned):
  //   x_bf    : M_PAD x 2048 bf16            (pad rows never written; 0xAA OK)
  //   qkvw_bf : 6144 x 2048 bf16
  //   projw_bf: 2048 x 2048 bf16
  //   qkv_bf  : 788 x 6144 bf16
  //   ao_bf   : M_PAD x 2048 bf16
  char* p = (char*)d_ws;
  ushort* x_bf    = (ushort*)p;                 p += (size_t)M_PAD * DIMC * 2;
  ushort* qkvw_bf = (ushort*)p;                 p += (size_t)3 * DIMC * DIMC * 2;
  ushort* projw_bf= (ushort*)p;                 p += (size_t)DIMC * DIMC * 2;
  ushort* qkv_bf  = (ushort*)p;                 p += (size_t)M_ROWS * 3 * DIMC * 2;
  ushort* ao_bf   = (ushort*)p;

  dim3 blk(256);
  // fp32 -> bf16 conversions
  {
    int n8 = M_ROWS * DIMC / 8;                          // 201728
    cvt_bf16<<<dim3((n8 + 255) / 256), blk, 0, stream>>>(x, x_bf, n8);
  }
  {
    int n8 = 3 * DIMC * DIMC / 8;                        // 1572864
    cvt_bf16<<<dim3(n8 / 256), blk, 0, stream>>>(qkv_w, qkvw_bf, n8);
  }
  {
    int n8 = DIMC * DIMC / 8;                            // 524288
    cvt_bf16<<<dim3(n8 / 256), blk, 0, stream>>>(proj_w, projw_bf, n8);
  }

  // QKV GEMM: (788 x 2048) @ (6144 x 2048)^T -> bf16 (788 x 6144)
  gemm_bt_bf16<1><<<dim3(M_PAD / 128, (3 * DIMC) / 128), blk, 0, stream>>>(
      x_bf, qkvw_bf, (void*)qkv_bf, nullptr, M_ROWS, 3 * DIMC, DIMC);

  // Local attention -> bf16 (788 x 2048)
  int total_waves = B_SZ * HEADS * N_SEQ;  // 25216
  local_attn<<<dim3((total_waves + 3) / 4), blk, 0, stream>>>(qkv_bf, ao_bf);

  // Proj GEMM: (788 x 2048) @ (2048 x 2048)^T + bias -> fp32 d_out
  gemm_bt_bf16<0><<<dim3(M_PAD / 128, DIMC / 128), blk, 0, stream>>>(
      ao_bf, projw_bf, (void*)out, proj_b, M_ROWS, DIMC, DIMC);
}

// Round 3
// 147.413 us; speedup vs baseline: 3.0658x; 1.1072x over previous
//
#include <hip/hip_runtime.h>
#include <math.h>

#define B_SZ   4
#define N_SEQ  197
#define DIMC   2048
#define HEADS  32
#define HD     64
#define WIN    8
#define M_ROWS (B_SZ * N_SEQ)   // 788
#define M_PAD  896               // 7 * 128

using f32x4 = __attribute__((ext_vector_type(4))) float;
using s16x8 = __attribute__((ext_vector_type(8))) short;

__device__ inline ushort f2bf(float f) {
  uint x = __float_as_uint(f);
  uint r = (x + 0x7fffu + ((x >> 16) & 1u)) >> 16;  // RNE
  return (ushort)r;
}
__device__ inline float bf2f(ushort u) {
  return __uint_as_float(((uint)u) << 16);
}

__device__ inline void gload16(const ushort* g, ushort* l) {
  __builtin_amdgcn_global_load_lds(
      (const __attribute__((address_space(1))) unsigned int*)g,
      (__attribute__((address_space(3))) unsigned int*)l, 16, 0, 0);
}

// ---------------- fp32 -> bf16 conversion (8 elems/thread) ------------------
__global__ __launch_bounds__(256)
void cvt_bf16(const float* __restrict__ src, ushort* __restrict__ dst, int n8) {
  int i = blockIdx.x * 256 + threadIdx.x;
  if (i >= n8) return;
  f32x4 a = ((const f32x4*)src)[2 * i];
  f32x4 b = ((const f32x4*)src)[2 * i + 1];
  ushort4 u0, u1;
  u0.x = f2bf(a.x); u0.y = f2bf(a.y); u0.z = f2bf(a.z); u0.w = f2bf(a.w);
  u1.x = f2bf(b.x); u1.y = f2bf(b.y); u1.z = f2bf(b.z); u1.w = f2bf(b.w);
  ((ushort4*)dst)[2 * i]     = u0;
  ((ushort4*)dst)[2 * i + 1] = u1;
}

// ---- GEMM (2-phase prefetch dbuf): C = A(bf16, MxK) @ Bw(bf16, NxK)^T ------
// A padded to multiple of 128 rows (readable garbage OK). Grid blocks % 8 == 0.
// OUT_BF16=1: write bf16 C; else fp32 C + bias[col].
template<int OUT_BF16>
__global__ __launch_bounds__(256)
void gemm_bt_bf16(const ushort* __restrict__ A, const ushort* __restrict__ Bw,
                  void* __restrict__ Cout, const float* __restrict__ bias,
                  int Mdim, int Ndim, int Kdim) {
  __shared__ ushort As[2][128 * 32];
  __shared__ ushort Bs[2][128 * 32];
  const int tid  = threadIdx.x;
  const int lane = tid & 63;
  const int wave = tid >> 6;

  // XCD-aware bijective swizzle (nwg % 8 == 0): consecutive logical blocks
  // (row-blocks sharing a B-stripe) land on the SAME XCD's L2.
  const int nwg  = gridDim.x * gridDim.y;
  const int phys = blockIdx.y * gridDim.x + blockIdx.x;
  const int cpx  = nwg >> 3;
  const int lg   = (phys & 7) * cpx + (phys >> 3);
  const int m0 = (lg % gridDim.x) * 128;
  const int n0 = (lg / gridDim.x) * 128;

  const int wr = (wave >> 1) * 64;   // wave output sub-tile (64x64)
  const int wc = (wave & 1) * 64;
  const int fr = lane & 15;
  const int kg = lane >> 4;
  const int srow = lane >> 2;        // staging: row within 16-row chunk
  const int scol = (lane & 3) * 8;   // staging: col (8 bf16 = 16B)

  f32x4 acc[4][4];
#pragma unroll
  for (int i = 0; i < 4; ++i)
#pragma unroll
    for (int j = 0; j < 4; ++j)
      acc[i][j] = (f32x4){0.f, 0.f, 0.f, 0.f};

  // staging source rows (chunk c = wave*2+q covers rows c*16 + srow)
  const ushort* Asrc0 = A  + (size_t)(m0 + wave * 32 + srow)      * Kdim + scol;
  const ushort* Asrc1 = A  + (size_t)(m0 + wave * 32 + 16 + srow) * Kdim + scol;
  const ushort* Bsrc0 = Bw + (size_t)(n0 + wave * 32 + srow)      * Kdim + scol;
  const ushort* Bsrc1 = Bw + (size_t)(n0 + wave * 32 + 16 + srow) * Kdim + scol;
  const int c0 = wave * 2 * 512;          // LDS elem offset of chunk wave*2
  const int c1 = (wave * 2 + 1) * 512;

  const int nt = Kdim >> 5;  // K-steps of 32

  // prologue: stage tile 0 into buf 0
  gload16(Asrc0, &As[0][c0]);
  gload16(Asrc1, &As[0][c1]);
  gload16(Bsrc0, &Bs[0][c0]);
  gload16(Bsrc1, &Bs[0][c1]);

  for (int t = 0; t < nt; ++t) {
    __syncthreads();   // drains vmcnt+lgkm: buf[t&1] ready, buf[t+1&1] reads done
    const int cur = t & 1;
    if (t + 1 < nt) {  // issue next tile's loads BEFORE compute (prefetch)
      const int nxt = cur ^ 1;
      const int k1 = (t + 1) << 5;
      gload16(Asrc0 + k1, &As[nxt][c0]);
      gload16(Asrc1 + k1, &As[nxt][c1]);
      gload16(Bsrc0 + k1, &Bs[nxt][c0]);
      gload16(Bsrc1 + k1, &Bs[nxt][c1]);
    }
    s16x8 af[4], bfr[4];
#pragma unroll
    for (int i = 0; i < 4; ++i)
      af[i] = *(const s16x8*)(&As[cur][(wr + i * 16 + fr) * 32 + kg * 8]);
#pragma unroll
    for (int j = 0; j < 4; ++j)
      bfr[j] = *(const s16x8*)(&Bs[cur][(wc + j * 16 + fr) * 32 + kg * 8]);
#pragma unroll
    for (int i = 0; i < 4; ++i)
#pragma unroll
      for (int j = 0; j < 4; ++j)
        acc[i][j] = __builtin_amdgcn_mfma_f32_16x16x32_bf16(af[i], bfr[j], acc[i][j], 0, 0, 0);
  }

  // C/D layout: col = lane&15, row = (lane>>4)*4 + reg
  const int crow_base = m0 + wr + (lane >> 4) * 4;
  const int ccol_base = n0 + wc + fr;
  if constexpr (OUT_BF16) {
    ushort* C = (ushort*)Cout;
#pragma unroll
    for (int j = 0; j < 4; ++j) {
      int col = ccol_base + j * 16;
#pragma unroll
      for (int i = 0; i < 4; ++i)
#pragma unroll
        for (int r = 0; r < 4; ++r) {
          int grow = crow_base + i * 16 + r;
          if (grow < Mdim) C[(size_t)grow * Ndim + col] = f2bf(acc[i][j][r]);
        }
    }
  } else {
    float* C = (float*)Cout;
#pragma unroll
    for (int j = 0; j < 4; ++j) {
      int col = ccol_base + j * 16;
      float bv = bias[col];
#pragma unroll
      for (int i = 0; i < 4; ++i)
#pragma unroll
        for (int r = 0; r < 4; ++r) {
          int grow = crow_base + i * 16 + r;
          if (grow < Mdim) C[(size_t)grow * Ndim + col] = acc[i][j][r] + bv;
        }
    }
  }
}

// ---------------- Local attention: one wave per (b, i, h) -------------------
// qkv bf16 layout: row = b*N+i (788 rows), col = three*2048 + h*64 + d
__global__ __launch_bounds__(256)
void local_attn(const ushort* __restrict__ qkv, ushort* __restrict__ ao) {
  const int gw = blockIdx.x * 4 + (threadIdx.x >> 6);
  if (gw >= B_SZ * HEADS * N_SEQ) return;
  const int lane = threadIdx.x & 63;
  const int h = gw % HEADS;
  const int t = gw / HEADS;
  const int i = t % N_SEQ;
  const int b = t / N_SEQ;
  const int row = b * N_SEQ + i;
  const size_t stride = 3 * DIMC;

  const float q = bf2f(qkv[(size_t)row * stride + h * HD + lane]) * 0.125f;  // fold scale
  int j0 = i - WIN; if (j0 < 0) j0 = 0;
  int j1 = i + WIN; if (j1 > N_SEQ) j1 = N_SEQ;   // [j0, j1)

  float s[16];
#pragma unroll
  for (int jj = 0; jj < 16; ++jj) {
    int j = j0 + jj;
    bool ok = (j < j1);
    int jc = ok ? j : (j1 - 1);
    float kd = bf2f(qkv[(size_t)(b * N_SEQ + jc) * stride + DIMC + h * HD + lane]);
    float p = q * kd;
#pragma unroll
    for (int o = 32; o > 0; o >>= 1) p += __shfl_xor(p, o);
    float d = fabsf((float)(i - j));
    float m = 1.0f - d * 0.0625f;    // (W - d/2)/W
    s[jj] = ok ? p * m : -INFINITY;
  }

  float mx = -INFINITY;
#pragma unroll
  for (int jj = 0; jj < 16; ++jj) mx = fmaxf(mx, s[jj]);
  float sum = 0.f;
#pragma unroll
  for (int jj = 0; jj < 16; ++jj) { float e = expf(s[jj] - mx); s[jj] = e; sum += e; }
  const float inv = 1.f / sum;

  float o = 0.f;
#pragma unroll
  for (int jj = 0; jj < 16; ++jj) {
    int j = j0 + jj;
    if (j < j1)
      o += s[jj] * bf2f(qkv[(size_t)(b * N_SEQ + j) * stride + 2 * DIMC + h * HD + lane]);
  }
  ao[(size_t)row * DIMC + h * HD + lane] = f2bf(o * inv);
}

// ----------------------------------------------------------------------------
extern "C" void kernel_launch(void* const* d_in, const int* in_sizes, int n_in,
                              void* d_out, int out_size, void* d_ws, size_t ws_size,
                              hipStream_t stream) {
  const float* x      = (const float*)d_in[0];
  const float* qkv_w  = (const float*)d_in[1];
  const float* proj_w = (const float*)d_in[2];
  const float* proj_b = (const float*)d_in[3];
  float* out = (float*)d_out;

  // ws layout (bf16 buffers, 256B aligned):
  char* p = (char*)d_ws;
  ushort* x_bf    = (ushort*)p;                 p += (size_t)M_PAD * DIMC * 2;
  ushort* qkvw_bf = (ushort*)p;                 p += (size_t)3 * DIMC * DIMC * 2;
  ushort* projw_bf= (ushort*)p;                 p += (size_t)DIMC * DIMC * 2;
  ushort* qkv_bf  = (ushort*)p;                 p += (size_t)M_ROWS * 3 * DIMC * 2;
  ushort* ao_bf   = (ushort*)p;

  dim3 blk(256);
  // fp32 -> bf16 conversions
  {
    int n8 = M_ROWS * DIMC / 8;
    cvt_bf16<<<dim3((n8 + 255) / 256), blk, 0, stream>>>(x, x_bf, n8);
  }
  {
    int n8 = 3 * DIMC * DIMC / 8;
    cvt_bf16<<<dim3(n8 / 256), blk, 0, stream>>>(qkv_w, qkvw_bf, n8);
  }
  {
    int n8 = DIMC * DIMC / 8;
    cvt_bf16<<<dim3(n8 / 256), blk, 0, stream>>>(proj_w, projw_bf, n8);
  }

  // QKV GEMM: (788 x 2048) @ (6144 x 2048)^T -> bf16 (788 x 6144)   [336 blocks]
  gemm_bt_bf16<1><<<dim3(M_PAD / 128, (3 * DIMC) / 128), blk, 0, stream>>>(
      x_bf, qkvw_bf, (void*)qkv_bf, nullptr, M_ROWS, 3 * DIMC, DIMC);

  // Local attention -> bf16 (788 x 2048)
  int total_waves = B_SZ * HEADS * N_SEQ;  // 25216
  local_attn<<<dim3((total_waves + 3) / 4), blk, 0, stream>>>(qkv_bf, ao_bf);

  // Proj GEMM: (788 x 2048) @ (2048 x 2048)^T + bias -> fp32 d_out  [112 blocks]
  gemm_bt_bf16<0><<<dim3(M_PAD / 128, DIMC / 128), blk, 0, stream>>>(
      ao_bf, projw_bf, (void*)out, proj_b, M_ROWS, DIMC, DIMC);
}

// Round 4
// 144.660 us; speedup vs baseline: 3.1241x; 1.0190x over previous
//
#include <hip/hip_runtime.h>
#include <math.h>

#define B_SZ   4
#define N_SEQ  197
#define DIMC   2048
#define HEADS  32
#define HD     64
#define WIN    8
#define M_ROWS (B_SZ * N_SEQ)   // 788
#define M_PAD  896               // 7 * 128

using f32x4 = __attribute__((ext_vector_type(4))) float;
using s16x8 = __attribute__((ext_vector_type(8))) short;

__device__ inline ushort f2bf(float f) {
  uint x = __float_as_uint(f);
  uint r = (x + 0x7fffu + ((x >> 16) & 1u)) >> 16;  // RNE
  return (ushort)r;
}
__device__ inline float bf2f(ushort u) {
  return __uint_as_float(((uint)u) << 16);
}

__device__ inline void gload16(const ushort* g, ushort* l) {
  __builtin_amdgcn_global_load_lds(
      (const __attribute__((address_space(1))) unsigned int*)g,
      (__attribute__((address_space(3))) unsigned int*)l, 16, 0, 0);
}

// ---------- fused fp32 -> bf16 conversion for x, qkv_w, proj_w --------------
#define NX (M_ROWS * DIMC / 8)        // 201728
#define NQ (3 * DIMC * DIMC / 8)      // 1572864
#define NP (DIMC * DIMC / 8)          // 524288

__global__ __launch_bounds__(256)
void cvt_all(const float* __restrict__ x,  const float* __restrict__ qw,
             const float* __restrict__ pw, ushort* __restrict__ xb,
             ushort* __restrict__ qwb, ushort* __restrict__ pwb) {
  int i = blockIdx.x * 256 + threadIdx.x;
  const float* src; ushort* dst; int idx;
  if (i < NX)           { src = x;  dst = xb;  idx = i; }
  else if (i < NX + NQ) { src = qw; dst = qwb; idx = i - NX; }
  else if (i < NX + NQ + NP) { src = pw; dst = pwb; idx = i - NX - NQ; }
  else return;
  f32x4 a = ((const f32x4*)src)[2 * idx];
  f32x4 b = ((const f32x4*)src)[2 * idx + 1];
  ushort4 u0, u1;
  u0.x = f2bf(a.x); u0.y = f2bf(a.y); u0.z = f2bf(a.z); u0.w = f2bf(a.w);
  u1.x = f2bf(b.x); u1.y = f2bf(b.y); u1.z = f2bf(b.z); u1.w = f2bf(b.w);
  ((ushort4*)dst)[2 * idx]     = u0;
  ((ushort4*)dst)[2 * idx + 1] = u1;
}

// ---- GEMM, depth-2 counted-vmcnt pipeline, 3 LDS buffers -------------------
// C = A(bf16, MxK) @ Bw(bf16, NxK)^T. A padded to mult of 128 rows.
// LDS slot-swizzle: 16B slot s of row r stored at slot s^(r&3); the global
// source column is pre-swizzled to match (gload_lds dest must stay linear).
template<int OUT_BF16>
__global__ __launch_bounds__(256)
void gemm_bt_bf16(const ushort* __restrict__ A, const ushort* __restrict__ Bw,
                  void* __restrict__ Cout, const float* __restrict__ bias,
                  int Mdim, int Ndim, int Kdim) {
  __shared__ ushort As[3][128 * 32];
  __shared__ ushort Bs[3][128 * 32];
  const int tid  = threadIdx.x;
  const int lane = tid & 63;
  const int wave = tid >> 6;

  // XCD-aware bijective swizzle (nwg % 8 == 0)
  const int nwg  = gridDim.x * gridDim.y;
  const int phys = blockIdx.y * gridDim.x + blockIdx.x;
  const int cpx  = nwg >> 3;
  const int lg   = (phys & 7) * cpx + (phys >> 3);
  const int m0 = (lg % gridDim.x) * 128;
  const int n0 = (lg / gridDim.x) * 128;

  const int wr = (wave >> 1) * 64;
  const int wc = (wave & 1) * 64;
  const int fr = lane & 15;
  const int kg = lane >> 4;
  const int srow = lane >> 2;                       // row within 16-row chunk
  const int scol = ((lane & 3) ^ (srow & 3)) * 8;   // pre-swizzled source slot

  f32x4 acc[4][4];
#pragma unroll
  for (int i = 0; i < 4; ++i)
#pragma unroll
    for (int j = 0; j < 4; ++j)
      acc[i][j] = (f32x4){0.f, 0.f, 0.f, 0.f};

  const ushort* Asrc0 = A  + (size_t)(m0 + wave * 32 + srow)      * Kdim + scol;
  const ushort* Asrc1 = A  + (size_t)(m0 + wave * 32 + 16 + srow) * Kdim + scol;
  const ushort* Bsrc0 = Bw + (size_t)(n0 + wave * 32 + srow)      * Kdim + scol;
  const ushort* Bsrc1 = Bw + (size_t)(n0 + wave * 32 + 16 + srow) * Kdim + scol;
  const int c0 = wave * 2 * 512;
  const int c1 = (wave * 2 + 1) * 512;

  const int nt = Kdim >> 5;

  auto STAGE = [&](int kk, int b) {
    const int k = kk << 5;
    gload16(Asrc0 + k, &As[b][c0]);
    gload16(Asrc1 + k, &As[b][c1]);
    gload16(Bsrc0 + k, &Bs[b][c0]);
    gload16(Bsrc1 + k, &Bs[b][c1]);
  };

  // prologue: tiles 0 and 1 in flight (8 loads/wave outstanding)
  STAGE(0, 0);
  STAGE(1, 1);

  int cur = 0;
  const int rdA = (kg ^ (fr & 3)) * 8;   // swizzled read slot (row&3 == fr&3)

  for (int t = 0; t < nt; ++t) {
    // wait for tile t's own 4 loads only (tile t+1's stay in flight),
    // then barrier -> all waves' tile-t loads visible; buf[cur+2] free.
    if (t < nt - 1) asm volatile("s_waitcnt vmcnt(4)" ::: "memory");
    else            asm volatile("s_waitcnt vmcnt(0)" ::: "memory");
    __builtin_amdgcn_s_barrier();
    __builtin_amdgcn_sched_barrier(0);

    if (t + 2 < nt) {
      int b2 = cur + 2; if (b2 >= 3) b2 -= 3;
      STAGE(t + 2, b2);
    }

    s16x8 af[4], bfr[4];
#pragma unroll
    for (int i = 0; i < 4; ++i)
      af[i] = *(const s16x8*)(&As[cur][(wr + i * 16 + fr) * 32 + rdA]);
#pragma unroll
    for (int j = 0; j < 4; ++j)
      bfr[j] = *(const s16x8*)(&Bs[cur][(wc + j * 16 + fr) * 32 + rdA]);
#pragma unroll
    for (int i = 0; i < 4; ++i)
#pragma unroll
      for (int j = 0; j < 4; ++j)
        acc[i][j] = __builtin_amdgcn_mfma_f32_16x16x32_bf16(af[i], bfr[j], acc[i][j], 0, 0, 0);

    cur += 1; if (cur >= 3) cur -= 3;
  }

  // C/D layout: col = lane&15, row = (lane>>4)*4 + reg
  const int crow_base = m0 + wr + (lane >> 4) * 4;
  const int ccol_base = n0 + wc + fr;
  if constexpr (OUT_BF16) {
    ushort* C = (ushort*)Cout;
#pragma unroll
    for (int j = 0; j < 4; ++j) {
      int col = ccol_base + j * 16;
#pragma unroll
      for (int i = 0; i < 4; ++i)
#pragma unroll
        for (int r = 0; r < 4; ++r) {
          int grow = crow_base + i * 16 + r;
          if (grow < Mdim) C[(size_t)grow * Ndim + col] = f2bf(acc[i][j][r]);
        }
    }
  } else {
    float* C = (float*)Cout;
#pragma unroll
    for (int j = 0; j < 4; ++j) {
      int col = ccol_base + j * 16;
      float bv = bias[col];
#pragma unroll
      for (int i = 0; i < 4; ++i)
#pragma unroll
        for (int r = 0; r < 4; ++r) {
          int grow = crow_base + i * 16 + r;
          if (grow < Mdim) C[(size_t)grow * Ndim + col] = acc[i][j][r] + bv;
        }
    }
  }
}

// ---------------- Local attention: one wave per (b, i, h) -------------------
__global__ __launch_bounds__(256)
void local_attn(const ushort* __restrict__ qkv, ushort* __restrict__ ao) {
  const int gw = blockIdx.x * 4 + (threadIdx.x >> 6);
  if (gw >= B_SZ * HEADS * N_SEQ) return;
  const int lane = threadIdx.x & 63;
  const int h = gw % HEADS;
  const int t = gw / HEADS;
  const int i = t % N_SEQ;
  const int b = t / N_SEQ;
  const int row = b * N_SEQ + i;
  const size_t stride = 3 * DIMC;

  const float q = bf2f(qkv[(size_t)row * stride + h * HD + lane]) * 0.125f;
  int j0 = i - WIN; if (j0 < 0) j0 = 0;
  int j1 = i + WIN; if (j1 > N_SEQ) j1 = N_SEQ;

  float s[16];
#pragma unroll
  for (int jj = 0; jj < 16; ++jj) {
    int j = j0 + jj;
    bool ok = (j < j1);
    int jc = ok ? j : (j1 - 1);
    float kd = bf2f(qkv[(size_t)(b * N_SEQ + jc) * stride + DIMC + h * HD + lane]);
    float p = q * kd;
#pragma unroll
    for (int o = 32; o > 0; o >>= 1) p += __shfl_xor(p, o);
    float d = fabsf((float)(i - j));
    float m = 1.0f - d * 0.0625f;
    s[jj] = ok ? p * m : -INFINITY;
  }

  float mx = -INFINITY;
#pragma unroll
  for (int jj = 0; jj < 16; ++jj) mx = fmaxf(mx, s[jj]);
  float sum = 0.f;
#pragma unroll
  for (int jj = 0; jj < 16; ++jj) { float e = expf(s[jj] - mx); s[jj] = e; sum += e; }
  const float inv = 1.f / sum;

  float o = 0.f;
#pragma unroll
  for (int jj = 0; jj < 16; ++jj) {
    int j = j0 + jj;
    if (j < j1)
      o += s[jj] * bf2f(qkv[(size_t)(b * N_SEQ + j) * stride + 2 * DIMC + h * HD + lane]);
  }
  ao[(size_t)row * DIMC + h * HD + lane] = f2bf(o * inv);
}

// ----------------------------------------------------------------------------
extern "C" void kernel_launch(void* const* d_in, const int* in_sizes, int n_in,
                              void* d_out, int out_size, void* d_ws, size_t ws_size,
                              hipStream_t stream) {
  const float* x      = (const float*)d_in[0];
  const float* qkv_w  = (const float*)d_in[1];
  const float* proj_w = (const float*)d_in[2];
  const float* proj_b = (const float*)d_in[3];
  float* out = (float*)d_out;

  char* p = (char*)d_ws;
  ushort* x_bf    = (ushort*)p;                 p += (size_t)M_PAD * DIMC * 2;
  ushort* qkvw_bf = (ushort*)p;                 p += (size_t)3 * DIMC * DIMC * 2;
  ushort* projw_bf= (ushort*)p;                 p += (size_t)DIMC * DIMC * 2;
  ushort* qkv_bf  = (ushort*)p;                 p += (size_t)M_ROWS * 3 * DIMC * 2;
  ushort* ao_bf   = (ushort*)p;

  dim3 blk(256);
  {
    int total = NX + NQ + NP;
    cvt_all<<<dim3((total + 255) / 256), blk, 0, stream>>>(
        x, qkv_w, proj_w, x_bf, qkvw_bf, projw_bf);
  }

  // QKV GEMM: (788 x 2048) @ (6144 x 2048)^T -> bf16 (788 x 6144)   [336 blocks]
  gemm_bt_bf16<1><<<dim3(M_PAD / 128, (3 * DIMC) / 128), blk, 0, stream>>>(
      x_bf, qkvw_bf, (void*)qkv_bf, nullptr, M_ROWS, 3 * DIMC, DIMC);

  // Local attention -> bf16 (788 x 2048)
  int total_waves = B_SZ * HEADS * N_SEQ;  // 25216
  local_attn<<<dim3((total_waves + 3) / 4), blk, 0, stream>>>(qkv_bf, ao_bf);

  // Proj GEMM: (788 x 2048) @ (2048 x 2048)^T + bias -> fp32 d_out  [112 blocks]
  gemm_bt_bf16<0><<<dim3(M_PAD / 128, DIMC / 128), blk, 0, stream>>>(
      ao_bf, projw_bf, (void*)out, proj_b, M_ROWS, DIMC, DIMC);
}

// Round 5
// 134.132 us; speedup vs baseline: 3.3693x; 1.0785x over previous
//
#include <hip/hip_runtime.h>
#include <math.h>

#define B_SZ   4
#define N_SEQ  197
#define DIMC   2048
#define HEADS  32
#define HD     64
#define WIN    8
#define M_ROWS (B_SZ * N_SEQ)   // 788
#define M_PAD  896               // 14 * 64 = 7 * 128

using f32x4 = __attribute__((ext_vector_type(4))) float;
using s16x8 = __attribute__((ext_vector_type(8))) short;

__device__ inline ushort f2bf(float f) {
  uint x = __float_as_uint(f);
  uint r = (x + 0x7fffu + ((x >> 16) & 1u)) >> 16;  // RNE
  return (ushort)r;
}
__device__ inline float bf2f(ushort u) {
  return __uint_as_float(((uint)u) << 16);
}

__device__ inline void gload16(const ushort* g, ushort* l) {
  __builtin_amdgcn_global_load_lds(
      (const __attribute__((address_space(1))) unsigned int*)g,
      (__attribute__((address_space(3))) unsigned int*)l, 16, 0, 0);
}

// ---------------- zero-init kernel (for atomic accumulation) ----------------
__global__ __launch_bounds__(256)
void zero_f32(float* __restrict__ p, int n4) {
  int i = blockIdx.x * 256 + threadIdx.x;
  int stride = gridDim.x * 256;
  for (int j = i; j < n4; j += stride)
    ((f32x4*)p)[j] = (f32x4){0.f, 0.f, 0.f, 0.f};
}

// ---------- fused fp32 -> bf16 conversion for x, qkv_w, proj_w --------------
#define NX (M_ROWS * DIMC / 8)        // 201728
#define NQ (3 * DIMC * DIMC / 8)      // 1572864
#define NP (DIMC * DIMC / 8)          // 524288

__global__ __launch_bounds__(256)
void cvt_all(const float* __restrict__ x,  const float* __restrict__ qw,
             const float* __restrict__ pw, ushort* __restrict__ xb,
             ushort* __restrict__ qwb, ushort* __restrict__ pwb) {
  int i = blockIdx.x * 256 + threadIdx.x;
  const float* src; ushort* dst; int idx;
  if (i < NX)           { src = x;  dst = xb;  idx = i; }
  else if (i < NX + NQ) { src = qw; dst = qwb; idx = i - NX; }
  else if (i < NX + NQ + NP) { src = pw; dst = pwb; idx = i - NX - NQ; }
  else return;
  f32x4 a = ((const f32x4*)src)[2 * idx];
  f32x4 b = ((const f32x4*)src)[2 * idx + 1];
  ushort4 u0, u1;
  u0.x = f2bf(a.x); u0.y = f2bf(a.y); u0.z = f2bf(a.z); u0.w = f2bf(a.w);
  u1.x = f2bf(b.x); u1.y = f2bf(b.y); u1.z = f2bf(b.z); u1.w = f2bf(b.w);
  ((ushort4*)dst)[2 * idx]     = u0;
  ((ushort4*)dst)[2 * idx + 1] = u1;
}

// ---- GEMM: C = A(bf16, MxK) @ Bw(bf16, NxK)^T, BMT x 128 tile --------------
// Depth-2 counted-vmcnt pipeline, 3 LDS buffers, per-z-slice XCD swizzle.
// BMT in {64,128}. OUT_ATOMIC=0: bf16 store. OUT_ATOMIC=1: fp32 atomicAdd
// (+bias[col] when blockIdx.z==0 and bias != nullptr). K range per block:
// [blockIdx.z*Ksplit, (blockIdx.z+1)*Ksplit), row stride Kfull.
template<int BMT, int OUT_ATOMIC>
__global__ __launch_bounds__(256)
void gemm_bt_bf16(const ushort* __restrict__ A, const ushort* __restrict__ Bw,
                  void* __restrict__ Cout, const float* __restrict__ bias,
                  int Mdim, int Ndim, int Kfull, int Ksplit) {
  constexpr int MI  = BMT / 32;            // M fragments per wave (2 or 4)
  constexpr int LPW = (BMT == 64) ? 3 : 4; // VMEM loads per wave per tile
  __shared__ ushort As[3][BMT * 32];
  __shared__ ushort Bs[3][128 * 32];
  const int tid  = threadIdx.x;
  const int lane = tid & 63;
  const int wave = tid >> 6;

  // XCD-aware bijective swizzle within each z-slice (nwg % 8 == 0)
  const int nwg  = gridDim.x * gridDim.y;
  const int phys = blockIdx.y * gridDim.x + blockIdx.x;
  const int cpx  = nwg >> 3;
  const int lg   = (phys & 7) * cpx + (phys >> 3);
  const int m0 = (lg % gridDim.x) * BMT;
  const int n0 = (lg / gridDim.x) * 128;
  const int koff = blockIdx.z * Ksplit;

  const int wr = (wave >> 1) * (BMT / 2);  // wave sub-tile: (BMT/2) x 64
  const int wc = (wave & 1) * 64;
  const int fr = lane & 15;
  const int kg = lane >> 4;
  const int srow = lane >> 2;                            // row in 16-row chunk
  const int scol = ((lane & 3) ^ ((srow >> 1) & 3)) * 8; // pre-swizzled src slot
  const int rdA  = (kg ^ ((fr >> 1) & 3)) * 8;           // matching read slot

  f32x4 acc[MI][4];
#pragma unroll
  for (int i = 0; i < MI; ++i)
#pragma unroll
    for (int j = 0; j < 4; ++j)
      acc[i][j] = (f32x4){0.f, 0.f, 0.f, 0.f};

  // staging sources
  const ushort* Asrc0;
  const ushort* Asrc1 = nullptr;
  if constexpr (BMT == 128) {
    Asrc0 = A + (size_t)(m0 + wave * 32 + srow)      * Kfull + koff + scol;
    Asrc1 = A + (size_t)(m0 + wave * 32 + 16 + srow) * Kfull + koff + scol;
  } else {
    Asrc0 = A + (size_t)(m0 + wave * 16 + srow)      * Kfull + koff + scol;
  }
  const ushort* Bsrc0 = Bw + (size_t)(n0 + wave * 32 + srow)      * Kfull + koff + scol;
  const ushort* Bsrc1 = Bw + (size_t)(n0 + wave * 32 + 16 + srow) * Kfull + koff + scol;

  const int nt = Ksplit >> 5;

  auto STAGE = [&](int kk, int b) {
    const int k = kk << 5;
    if constexpr (BMT == 128) {
      gload16(Asrc0 + k, &As[b][wave * 1024]);
      gload16(Asrc1 + k, &As[b][wave * 1024 + 512]);
    } else {
      gload16(Asrc0 + k, &As[b][wave * 512]);
    }
    gload16(Bsrc0 + k, &Bs[b][wave * 1024]);
    gload16(Bsrc1 + k, &Bs[b][wave * 1024 + 512]);
  };

  // prologue: tiles 0 and 1 in flight (2*LPW outstanding per wave)
  STAGE(0, 0);
  STAGE(1, 1);

  int cur = 0;
  for (int t = 0; t < nt; ++t) {
    // wait for tile t's own LPW loads only; tile t+1's stay in flight
    if (t < nt - 1) {
      if constexpr (LPW == 3) asm volatile("s_waitcnt vmcnt(3)" ::: "memory");
      else                    asm volatile("s_waitcnt vmcnt(4)" ::: "memory");
    } else {
      asm volatile("s_waitcnt vmcnt(0)" ::: "memory");
    }
    __builtin_amdgcn_s_barrier();
    __builtin_amdgcn_sched_barrier(0);

    if (t + 2 < nt) {
      int b2 = cur + 2; if (b2 >= 3) b2 -= 3;
      STAGE(t + 2, b2);
    }

    s16x8 af[MI], bfr[4];
#pragma unroll
    for (int i = 0; i < MI; ++i)
      af[i] = *(const s16x8*)(&As[cur][(wr + i * 16 + fr) * 32 + rdA]);
#pragma unroll
    for (int j = 0; j < 4; ++j)
      bfr[j] = *(const s16x8*)(&Bs[cur][(wc + j * 16 + fr) * 32 + rdA]);
#pragma unroll
    for (int i = 0; i < MI; ++i)
#pragma unroll
      for (int j = 0; j < 4; ++j)
        acc[i][j] = __builtin_amdgcn_mfma_f32_16x16x32_bf16(af[i], bfr[j], acc[i][j], 0, 0, 0);

    cur += 1; if (cur >= 3) cur -= 3;
  }

  // C/D layout: col = lane&15, row = (lane>>4)*4 + reg
  const int crow_base = m0 + wr + (lane >> 4) * 4;
  const int ccol_base = n0 + wc + fr;
  if constexpr (OUT_ATOMIC) {
    float* C = (float*)Cout;
    const bool addb = (bias != nullptr) && (blockIdx.z == 0);
#pragma unroll
    for (int j = 0; j < 4; ++j) {
      int col = ccol_base + j * 16;
      float bv = addb ? bias[col] : 0.f;
#pragma unroll
      for (int i = 0; i < MI; ++i)
#pragma unroll
        for (int r = 0; r < 4; ++r) {
          int grow = crow_base + i * 16 + r;
          if (grow < Mdim) atomicAdd(&C[(size_t)grow * Ndim + col], acc[i][j][r] + bv);
        }
    }
  } else {
    ushort* C = (ushort*)Cout;
#pragma unroll
    for (int j = 0; j < 4; ++j) {
      int col = ccol_base + j * 16;
#pragma unroll
      for (int i = 0; i < MI; ++i)
#pragma unroll
        for (int r = 0; r < 4; ++r) {
          int grow = crow_base + i * 16 + r;
          if (grow < Mdim) C[(size_t)grow * Ndim + col] = f2bf(acc[i][j][r]);
        }
    }
  }
}

// ---------------- Local attention: one wave per (b, i, h) -------------------
__global__ __launch_bounds__(256)
void local_attn(const ushort* __restrict__ qkv, ushort* __restrict__ ao) {
  const int gw = blockIdx.x * 4 + (threadIdx.x >> 6);
  if (gw >= B_SZ * HEADS * N_SEQ) return;
  const int lane = threadIdx.x & 63;
  const int h = gw % HEADS;
  const int t = gw / HEADS;
  const int i = t % N_SEQ;
  const int b = t / N_SEQ;
  const int row = b * N_SEQ + i;
  const size_t stride = 3 * DIMC;

  const float q = bf2f(qkv[(size_t)row * stride + h * HD + lane]) * 0.125f;
  int j0 = i - WIN; if (j0 < 0) j0 = 0;
  int j1 = i + WIN; if (j1 > N_SEQ) j1 = N_SEQ;

  float s[16];
#pragma unroll
  for (int jj = 0; jj < 16; ++jj) {
    int j = j0 + jj;
    bool ok = (j < j1);
    int jc = ok ? j : (j1 - 1);
    float kd = bf2f(qkv[(size_t)(b * N_SEQ + jc) * stride + DIMC + h * HD + lane]);
    float p = q * kd;
#pragma unroll
    for (int o = 32; o > 0; o >>= 1) p += __shfl_xor(p, o);
    float d = fabsf((float)(i - j));
    float m = 1.0f - d * 0.0625f;
    s[jj] = ok ? p * m : -INFINITY;
  }

  float mx = -INFINITY;
#pragma unroll
  for (int jj = 0; jj < 16; ++jj) mx = fmaxf(mx, s[jj]);
  float sum = 0.f;
#pragma unroll
  for (int jj = 0; jj < 16; ++jj) { float e = expf(s[jj] - mx); s[jj] = e; sum += e; }
  const float inv = 1.f / sum;

  float o = 0.f;
#pragma unroll
  for (int jj = 0; jj < 16; ++jj) {
    int j = j0 + jj;
    if (j < j1)
      o += s[jj] * bf2f(qkv[(size_t)(b * N_SEQ + j) * stride + 2 * DIMC + h * HD + lane]);
  }
  ao[(size_t)row * DIMC + h * HD + lane] = f2bf(o * inv);
}

// ----------------------------------------------------------------------------
extern "C" void kernel_launch(void* const* d_in, const int* in_sizes, int n_in,
                              void* d_out, int out_size, void* d_ws, size_t ws_size,
                              hipStream_t stream) {
  const float* x      = (const float*)d_in[0];
  const float* qkv_w  = (const float*)d_in[1];
  const float* proj_w = (const float*)d_in[2];
  const float* proj_b = (const float*)d_in[3];
  float* out = (float*)d_out;

  char* p = (char*)d_ws;
  ushort* x_bf    = (ushort*)p;                 p += (size_t)M_PAD * DIMC * 2;
  ushort* qkvw_bf = (ushort*)p;                 p += (size_t)3 * DIMC * DIMC * 2;
  ushort* projw_bf= (ushort*)p;                 p += (size_t)DIMC * DIMC * 2;
  ushort* qkv_bf  = (ushort*)p;                 p += (size_t)M_ROWS * 3 * DIMC * 2;
  ushort* ao_bf   = (ushort*)p;

  dim3 blk(256);

  // zero d_out (proj accumulates into it atomically)
  zero_f32<<<dim3(512), blk, 0, stream>>>(out, M_ROWS * DIMC / 4);

  {
    int total = NX + NQ + NP;
    cvt_all<<<dim3((total + 255) / 256), blk, 0, stream>>>(
        x, qkv_w, proj_w, x_bf, qkvw_bf, projw_bf);
  }

  // QKV GEMM: 64x128 tiles, grid (14,48) = 672 blocks (~2.6/CU), bf16 out
  gemm_bt_bf16<64, 0><<<dim3(M_PAD / 64, (3 * DIMC) / 128, 1), blk, 0, stream>>>(
      x_bf, qkvw_bf, (void*)qkv_bf, nullptr, M_ROWS, 3 * DIMC, DIMC, DIMC);

  // Local attention -> bf16 (788 x 2048)
  int total_waves = B_SZ * HEADS * N_SEQ;  // 25216
  local_attn<<<dim3((total_waves + 3) / 4), blk, 0, stream>>>(qkv_bf, ao_bf);

  // Proj GEMM: 128x128 tiles, split-K=4, grid (7,16,4) = 448 blocks,
  // fp32 atomicAdd into zeroed d_out, bias added by z==0 splits.
  gemm_bt_bf16<128, 1><<<dim3(M_PAD / 128, DIMC / 128, 4), blk, 0, stream>>>(
      ao_bf, projw_bf, (void*)out, proj_b, M_ROWS, DIMC, DIMC, DIMC / 4);
}